// Round 4
// baseline (963.218 us; speedup 1.0000x reference)
//
#include <hip/hip_runtime.h>
#include <hip/hip_fp16.h>
#include <math.h>

// ---------------------------------------------------------------------------
// SimGNN forward on MI355X — combined-graph pipeline, fp16 gather operands.
// M = 2N nodes (graph-2 ids offset +N). One CSR build (col = src only, 4B).
// All node-feature intermediates stored as __half (gather traffic halved);
// accumulation and weights stay fp32. Dense GEMMs are separate kernels
// (fusing them into the bandwidth-bound gather kernels regressed in R3).
//   convert: xh = fp16(f1|f2)          [M,64]
//   agg64h : t = A xh                  [M,64] fp16   (LLC-bw-bound gather)
//   gemm64h: x1 = relu(t@W1+b1)        [M,64] fp16
//   agg64h : t = A x1                  [M,64] fp16
//   gemm64_32h: h3 = relu(t@W2+b2)@W3  [M,32] fp16
//   agg32h : a3 = A h3 + b3, msum+=colsum(a3)   [M,32] fp16 + fp32 colsums
//   ctx = tanh(msum/N @ W_att); pooled = a3^T sigmoid(a3 ctx); NTN -> 16 out
// A applied as out[v] = dinv[v]*( x[v]*dinv[v] + sum_{(u->v)} x[u]*dinv[u] ).
// ---------------------------------------------------------------------------

__global__ void count2_kernel(const int* __restrict__ ei1, const int* __restrict__ ei2,
                              int E, int N, int* __restrict__ counts) {
    int i = blockIdx.x * blockDim.x + threadIdx.x;
    if (i < E)          atomicAdd(&counts[ei1[E + i]], 1);
    else if (i < 2 * E) atomicAdd(&counts[ei2[E + (i - E)] + N], 1);
}

// ---- 3-phase scan over counts[M] -> row_ptr[M+1], dinv[M] ----
__global__ void scanA_kernel(const int* __restrict__ counts, int* __restrict__ bsum, int M) {
    __shared__ int sh[256];
    int t = threadIdx.x;
    int base = blockIdx.x * 1024 + t * 4;
    int s = 0;
    #pragma unroll
    for (int k = 0; k < 4; ++k) { int idx = base + k; if (idx < M) s += counts[idx]; }
    sh[t] = s;
    __syncthreads();
    for (int off = 128; off; off >>= 1) {
        if (t < off) sh[t] += sh[t + off];
        __syncthreads();
    }
    if (t == 0) bsum[blockIdx.x] = sh[0];
}

__global__ void scanB_kernel(int* __restrict__ bsum, int P, int* __restrict__ row_ptr, int M) {
    __shared__ int sh[256];
    int t = threadIdx.x;
    sh[t] = (t < P) ? bsum[t] : 0;
    __syncthreads();
    for (int off = 1; off < 256; off <<= 1) {
        int v = (t >= off) ? sh[t - off] : 0;
        __syncthreads();
        sh[t] += v;
        __syncthreads();
    }
    if (t < P) bsum[t] = (t == 0) ? 0 : sh[t - 1];
    if (t == 255) row_ptr[M] = sh[255];
}

__global__ void scanC_kernel(const int* __restrict__ counts, const int* __restrict__ bsum,
                             int* __restrict__ row_ptr, float* __restrict__ dinv, int M) {
    __shared__ int sh[256];
    int t = threadIdx.x;
    int base = blockIdx.x * 1024 + t * 4;
    int c[4];
    int s = 0;
    #pragma unroll
    for (int k = 0; k < 4; ++k) { int idx = base + k; c[k] = (idx < M) ? counts[idx] : 0; s += c[k]; }
    sh[t] = s;
    __syncthreads();
    for (int off = 1; off < 256; off <<= 1) {
        int v = (t >= off) ? sh[t - off] : 0;
        __syncthreads();
        sh[t] += v;
        __syncthreads();
    }
    int run = bsum[blockIdx.x] + ((t == 0) ? 0 : sh[t - 1]);
    #pragma unroll
    for (int k = 0; k < 4; ++k) {
        int idx = base + k;
        if (idx < M) {
            row_ptr[idx] = run;
            dinv[idx] = rsqrtf((float)(c[k] + 1));
            run += c[k];
        }
    }
}

// counts doubles as the per-row cursor; one 4B scattered store per edge.
__global__ void fill2_kernel(const int* __restrict__ ei1, const int* __restrict__ ei2,
                             int E, int N, const int* __restrict__ row_ptr,
                             int* __restrict__ counts, int* __restrict__ col) {
    int i = blockIdx.x * blockDim.x + threadIdx.x;
    int src, dst;
    if (i < E)          { src = ei1[i];             dst = ei1[E + i]; }
    else if (i < 2 * E) { src = ei2[i - E] + N;     dst = ei2[E + (i - E)] + N; }
    else return;
    int p = atomicSub(&counts[dst], 1) - 1;
    col[row_ptr[dst] + p] = src;
}

// fp32 [N,64]x2 -> fp16 [M,64]; 4 elements per thread.
__global__ void convert_kernel(const float* __restrict__ f1, const float* __restrict__ f2,
                               __half* __restrict__ xh, int n /* = N*64 */) {
    int i4 = (blockIdx.x * blockDim.x + threadIdx.x) * 4;
    if (i4 >= 2 * n) return;
    const float* src = (i4 < n) ? (f1 + i4) : (f2 + (i4 - n));
    float4 v = *(const float4*)src;
    *(__half2*)(xh + i4)     = __floats2half2_rn(v.x, v.y);
    *(__half2*)(xh + i4 + 2) = __floats2half2_rn(v.z, v.w);
}

// Wave per node; lane = feature (64-wide). fp16 gather, fp32 accumulate.
__global__ void agg64h_kernel(const __half* __restrict__ x, __half* __restrict__ out,
                              const int* __restrict__ row_ptr, const int* __restrict__ col,
                              const float* __restrict__ dinv, int M) {
    int gt = blockIdx.x * blockDim.x + threadIdx.x;
    int v = gt >> 6;
    int lane = gt & 63;
    if (v >= M) return;
    float dv = dinv[v];
    float acc = __half2float(x[(size_t)v * 64 + lane]) * dv;   // self-loop
    int s = row_ptr[v], e = row_ptr[v + 1];
    int i = s;
    for (; i + 4 <= e; i += 4) {
        int u0 = col[i], u1 = col[i + 1], u2 = col[i + 2], u3 = col[i + 3];
        float w0 = dinv[u0], w1 = dinv[u1], w2 = dinv[u2], w3 = dinv[u3];
        float a0 = __half2float(x[(size_t)u0 * 64 + lane]);
        float a1 = __half2float(x[(size_t)u1 * 64 + lane]);
        float a2 = __half2float(x[(size_t)u2 * 64 + lane]);
        float a3 = __half2float(x[(size_t)u3 * 64 + lane]);
        acc += a0 * w0 + a1 * w1 + a2 * w2 + a3 * w3;
    }
    for (; i < e; ++i) {
        int u = col[i];
        acc += __half2float(x[(size_t)u * 64 + lane]) * dinv[u];
    }
    out[(size_t)v * 64 + lane] = __float2half(acc * dv);
}

// Dense: out[v][j] = relu(sum_k in[v][k]*W[k][j] + b[j]); grid-stride waves.
__global__ void gemm64h_kernel(const __half* __restrict__ in, __half* __restrict__ out,
                               const float* __restrict__ W, const float* __restrict__ b,
                               int M, int num_waves) {
    __shared__ float Ws[64 * 64];
    for (int i = threadIdx.x; i < 64 * 64; i += blockDim.x) Ws[i] = W[i];
    __syncthreads();
    int lane = threadIdx.x & 63;
    int wid = (blockIdx.x * blockDim.x + threadIdx.x) >> 6;
    float bj = b[lane];
    for (int v = wid; v < M; v += num_waves) {
        float r = __half2float(in[(size_t)v * 64 + lane]);
        float acc = bj;
        #pragma unroll
        for (int k = 0; k < 64; ++k) acc += __shfl(r, k) * Ws[k * 64 + lane];
        out[(size_t)v * 64 + lane] = __float2half(fmaxf(acc, 0.f));
    }
}

// Dense: h3 = relu(in@W2+b2)@W3, 64->32; grid-stride waves.
__global__ void gemm64_32h_kernel(const __half* __restrict__ in, __half* __restrict__ out,
                                  const float* __restrict__ W2, const float* __restrict__ b2,
                                  const float* __restrict__ W3, int M, int num_waves) {
    __shared__ float Ws2[64 * 64];
    __shared__ float Ws3[64 * 32];
    for (int i = threadIdx.x; i < 64 * 64; i += blockDim.x) Ws2[i] = W2[i];
    for (int i = threadIdx.x; i < 64 * 32; i += blockDim.x) Ws3[i] = W3[i];
    __syncthreads();
    int lane = threadIdx.x & 63;
    int j32 = lane & 31;
    int wid = (blockIdx.x * blockDim.x + threadIdx.x) >> 6;
    float bj = b2[lane];
    for (int v = wid; v < M; v += num_waves) {
        float r = __half2float(in[(size_t)v * 64 + lane]);
        float x2v = bj;
        #pragma unroll
        for (int k = 0; k < 64; ++k) x2v += __shfl(r, k) * Ws2[k * 64 + lane];
        x2v = fmaxf(x2v, 0.f);
        float h = 0.f;
        #pragma unroll
        for (int k = 0; k < 64; ++k) h += __shfl(x2v, k) * Ws3[k * 32 + j32];
        if (lane < 32) out[(size_t)v * 32 + lane] = __float2half(h);
    }
}

// agg32 (+bias) on fp16 h3 (64B rows!), a3 out fp16, fused per-graph colsums.
__global__ void agg32h_colsum_kernel(const __half* __restrict__ h, __half* __restrict__ out,
                                     const int* __restrict__ row_ptr, const int* __restrict__ col,
                                     const float* __restrict__ dinv, const float* __restrict__ b,
                                     float* __restrict__ msum, int N, int halfgrid) {
    int g = (blockIdx.x >= halfgrid) ? 1 : 0;
    int bid = blockIdx.x - g * halfgrid;
    int t = threadIdx.x;
    int lane = t & 31;
    int hw = (bid * blockDim.x + t) >> 5;
    int nhw = (halfgrid * blockDim.x) >> 5;
    float bl = b[lane];
    float csum = 0.f;
    int base = g * N;
    for (int vv = hw; vv < N; vv += nhw) {
        int v = base + vv;
        float dv = dinv[v];
        float acc = __half2float(h[(size_t)v * 32 + lane]) * dv;
        int s = row_ptr[v], e = row_ptr[v + 1];
        int i = s;
        for (; i + 4 <= e; i += 4) {
            int u0 = col[i], u1 = col[i + 1], u2 = col[i + 2], u3 = col[i + 3];
            float w0 = dinv[u0], w1 = dinv[u1], w2 = dinv[u2], w3 = dinv[u3];
            acc += __half2float(h[(size_t)u0 * 32 + lane]) * w0
                 + __half2float(h[(size_t)u1 * 32 + lane]) * w1
                 + __half2float(h[(size_t)u2 * 32 + lane]) * w2
                 + __half2float(h[(size_t)u3 * 32 + lane]) * w3;
        }
        for (; i < e; ++i) {
            int u = col[i];
            acc += __half2float(h[(size_t)u * 32 + lane]) * dinv[u];
        }
        float o = acc * dv + bl;
        out[(size_t)v * 32 + lane] = __float2half(o);
        csum += o;
    }
    __shared__ float sp[256];
    sp[t] = csum;
    __syncthreads();
    if (t < 32) {
        float s = 0.f;
        for (int w = 0; w < 8; ++w) s += sp[w * 32 + t];
        atomicAdd(&msum[g * 32 + t], s);
    }
}

// ctx[g*32+j] = tanh( sum_i (msum[g*32+i]/N) * W_att[i][j] ); one 64-thread block.
__global__ void ctx2_kernel(const float* __restrict__ msum, const float* __restrict__ W_att,
                            float* __restrict__ ctx, int N) {
    int t = threadIdx.x;
    if (t >= 64) return;
    int g = t >> 5, j = t & 31;
    float invN = 1.f / (float)N;
    float acc = 0.f;
    for (int i = 0; i < 32; ++i) acc += (msum[g * 32 + i] * invN) * W_att[i * 32 + j];
    ctx[g * 32 + j] = tanhf(acc);
}

// pooled[g*32+j] = sum_n sigmoid(a3[n].ctx_g) * a3[n][j]; a3 in fp16.
__global__ void pool2h_kernel(const __half* __restrict__ a3, const float* __restrict__ ctx,
                              float* __restrict__ pooled, int N, int halfgrid) {
    int g = (blockIdx.x >= halfgrid) ? 1 : 0;
    int bid = blockIdx.x - g * halfgrid;
    int t = threadIdx.x;
    int j = t & 31;
    int hw = (bid * blockDim.x + t) >> 5;
    int nhw = (halfgrid * blockDim.x) >> 5;
    const __half* base = a3 + (size_t)g * N * 32;
    float cj = ctx[g * 32 + j];
    float local = 0.f;
    for (int n = hw; n < N; n += nhw) {
        float v = __half2float(base[(size_t)n * 32 + j]);
        float d = v * cj;
        #pragma unroll
        for (int off = 16; off; off >>= 1) d += __shfl_xor(d, off);  // stays in 32-lane half
        float s = 1.f / (1.f + __expf(-d));
        local += s * v;
    }
    __shared__ float sp[256];
    sp[t] = local;
    __syncthreads();
    if (t < 32) {
        float s = 0.f;
        for (int w = 0; w < 8; ++w) s += sp[w * 32 + t];
        atomicAdd(&pooled[g * 32 + t], s);
    }
}

// NTN: out[k] = relu( sum_ij e1[i] W_tn[i,j,k] e2[j] + W_block[k].[e1;e2] + b_tn[k] )
__global__ void ntn_kernel(const float* __restrict__ p1, const float* __restrict__ p2,
                           const float* __restrict__ W_tn, const float* __restrict__ W_block,
                           const float* __restrict__ b_tn, float* __restrict__ out) {
    int k = threadIdx.x;
    if (k >= 16) return;
    float sc = 0.f;
    for (int i = 0; i < 32; ++i) {
        float e1 = p1[i];
        for (int j = 0; j < 32; ++j) sc += e1 * W_tn[i * 512 + j * 16 + k] * p2[j];
    }
    float bl = 0.f;
    for (int j = 0; j < 32; ++j)
        bl += W_block[k * 64 + j] * p1[j] + W_block[k * 64 + 32 + j] * p2[j];
    float v = sc + bl + b_tn[k];
    out[k] = v > 0.f ? v : 0.f;
}

extern "C" void kernel_launch(void* const* d_in, const int* in_sizes, int n_in,
                              void* d_out, int out_size, void* d_ws, size_t ws_size,
                              hipStream_t stream) {
    const float* f1     = (const float*)d_in[0];
    const int*   ei1    = (const int*)  d_in[1];
    const float* f2     = (const float*)d_in[2];
    const int*   ei2    = (const int*)  d_in[3];
    const float* W1     = (const float*)d_in[4];
    const float* b1     = (const float*)d_in[5];
    const float* W2     = (const float*)d_in[6];
    const float* b2     = (const float*)d_in[7];
    const float* W3     = (const float*)d_in[8];
    const float* b3     = (const float*)d_in[9];
    const float* W_att  = (const float*)d_in[10];
    const float* W_tn   = (const float*)d_in[11];
    const float* W_blk  = (const float*)d_in[12];
    const float* b_tn   = (const float*)d_in[13];

    int N = in_sizes[0] / 64;
    int E = in_sizes[1] / 2;
    int M = 2 * N;
    int E2 = 2 * E;

    char* ws = (char*)d_ws;
    size_t off = 0;
    auto alloc = [&](size_t bytes) -> void* {
        void* p = ws + off;
        off += (bytes + 511) & ~(size_t)511;
        return p;
    };
    __half* xh      = (__half*)alloc((size_t)M * 64 * sizeof(__half));  // fp16 inputs
    __half* bufT    = (__half*)alloc((size_t)M * 64 * sizeof(__half));  // t1 / t2
    __half* bufX    = (__half*)alloc((size_t)M * 64 * sizeof(__half));  // x1; a3 reuses
    __half* bufH    = (__half*)alloc((size_t)M * 32 * sizeof(__half));  // h3
    int*   col      = (int*)   alloc((size_t)E2 * sizeof(int));
    int*   row_ptr  = (int*)   alloc((size_t)(M + 1) * sizeof(int));
    int*   counts   = (int*)   alloc((size_t)M * sizeof(int));
    float* dinv     = (float*) alloc((size_t)M * sizeof(float));
    int*   bsum     = (int*)   alloc(256 * sizeof(int));
    float* smalls   = (float*) alloc(256 * sizeof(float));
    float* msum   = smalls;        // [64]
    float* pooled = smalls + 64;   // [64]
    float* ctx    = smalls + 128;  // [64]
    __half* a3h   = bufX;          // a3 [M,32] fp16 (reuse x1 buffer)

    hipMemsetAsync(smalls, 0, 256 * sizeof(float), stream);
    hipMemsetAsync(counts, 0, (size_t)M * sizeof(int), stream);

    int eb = (E2 + 255) / 256;
    int P  = (M + 1023) / 1024;

    // CSR build
    count2_kernel<<<eb, 256, 0, stream>>>(ei1, ei2, E, N, counts);
    scanA_kernel<<<P, 256, 0, stream>>>(counts, bsum, M);
    scanB_kernel<<<1, 256, 0, stream>>>(bsum, P, row_ptr, M);
    scanC_kernel<<<P, 256, 0, stream>>>(counts, bsum, row_ptr, dinv, M);
    fill2_kernel<<<eb, 256, 0, stream>>>(ei1, ei2, E, N, row_ptr, counts, col);

    // fp16 input table
    int cvb = (M * 64 / 4 + 255) / 256;
    convert_kernel<<<cvb, 256, 0, stream>>>(f1, f2, xh, N * 64);

    // GCN stack (agg = gather-only, gemm = dense)
    int nb64 = (M * 64 + 255) / 256;       // wave-per-node
    const int GB = 1024;                   // dense gemm grid
    int num_waves = GB * (256 / 64);
    agg64h_kernel<<<nb64, 256, 0, stream>>>(xh, bufT, row_ptr, col, dinv, M);
    gemm64h_kernel<<<GB, 256, 0, stream>>>(bufT, bufX, W1, b1, M, num_waves);
    agg64h_kernel<<<nb64, 256, 0, stream>>>(bufX, bufT, row_ptr, col, dinv, M);
    gemm64_32h_kernel<<<GB, 256, 0, stream>>>(bufT, bufH, W2, b2, W3, M, num_waves);

    const int HG = 512;
    agg32h_colsum_kernel<<<2 * HG, 256, 0, stream>>>(bufH, a3h, row_ptr, col, dinv, b3, msum, N, HG);

    ctx2_kernel<<<1, 64, 0, stream>>>(msum, W_att, ctx, N);
    pool2h_kernel<<<2 * 256, 256, 0, stream>>>(a3h, ctx, pooled, N, 256);
    ntn_kernel<<<1, 64, 0, stream>>>(pooled, pooled + 32, W_tn, W_blk, b_tn, (float*)d_out);
}

// Round 5
// 803.057 us; speedup vs baseline: 1.1994x; 1.1994x over previous
//
#include <hip/hip_runtime.h>
#include <math.h>

// ---------------------------------------------------------------------------
// SimGNN forward on MI355X — combined-graph pipeline (R2 skeleton + pre-scaled
// tables). M = 2N nodes (graph-2 ids offset +N). One CSR build, col = src only.
//
// Key trick: every gathered table is pre-scaled by dinv, so
//   (A x)[v] = dinv[v] * ( xs[v] + sum_{(u->v)} xs[u] ),  xs[u] = x[u]*dinv[u]
// -> agg inner loop is PURE gather+add (no per-edge weight, no dinv load).
// The *dinv scaling of the next layer's table is folded into the GEMM
// epilogue, which already writes every row.
//   scale0 : xs0 = x0 * dinv                    [M,64]
//   agg64  : t1 = rowsum(xs0) * dinv            [M,64]
//   gemm64 : xs1 = relu(t1@W1+b1) * dinv        [M,64]
//   agg64  : t2 = rowsum(xs1) * dinv            [M,64]
//   gemm   : h3s = (relu(t2@W2+b2)@W3) * dinv   [M,32]
//   agg32  : a3 = rowsum(h3s)*dinv + b3, msum += colsum(a3)   [M,32]
//   ctx = tanh(msum/N @ W_att); pooled = a3^T sigmoid(a3 ctx); NTN -> 16 out
// ---------------------------------------------------------------------------

__global__ void count2_kernel(const int* __restrict__ ei1, const int* __restrict__ ei2,
                              int E, int N, int* __restrict__ counts) {
    int i = blockIdx.x * blockDim.x + threadIdx.x;
    if (i < E)          atomicAdd(&counts[ei1[E + i]], 1);
    else if (i < 2 * E) atomicAdd(&counts[ei2[E + (i - E)] + N], 1);
}

// ---- 3-phase scan over counts[M] -> row_ptr[M+1], dinv[M] ----
__global__ void scanA_kernel(const int* __restrict__ counts, int* __restrict__ bsum, int M) {
    __shared__ int sh[256];
    int t = threadIdx.x;
    int base = blockIdx.x * 1024 + t * 4;
    int s = 0;
    #pragma unroll
    for (int k = 0; k < 4; ++k) { int idx = base + k; if (idx < M) s += counts[idx]; }
    sh[t] = s;
    __syncthreads();
    for (int off = 128; off; off >>= 1) {
        if (t < off) sh[t] += sh[t + off];
        __syncthreads();
    }
    if (t == 0) bsum[blockIdx.x] = sh[0];
}

__global__ void scanB_kernel(int* __restrict__ bsum, int P, int* __restrict__ row_ptr, int M) {
    __shared__ int sh[256];
    int t = threadIdx.x;
    sh[t] = (t < P) ? bsum[t] : 0;
    __syncthreads();
    for (int off = 1; off < 256; off <<= 1) {
        int v = (t >= off) ? sh[t - off] : 0;
        __syncthreads();
        sh[t] += v;
        __syncthreads();
    }
    if (t < P) bsum[t] = (t == 0) ? 0 : sh[t - 1];
    if (t == 255) row_ptr[M] = sh[255];
}

__global__ void scanC_kernel(const int* __restrict__ counts, const int* __restrict__ bsum,
                             int* __restrict__ row_ptr, float* __restrict__ dinv, int M) {
    __shared__ int sh[256];
    int t = threadIdx.x;
    int base = blockIdx.x * 1024 + t * 4;
    int c[4];
    int s = 0;
    #pragma unroll
    for (int k = 0; k < 4; ++k) { int idx = base + k; c[k] = (idx < M) ? counts[idx] : 0; s += c[k]; }
    sh[t] = s;
    __syncthreads();
    for (int off = 1; off < 256; off <<= 1) {
        int v = (t >= off) ? sh[t - off] : 0;
        __syncthreads();
        sh[t] += v;
        __syncthreads();
    }
    int run = bsum[blockIdx.x] + ((t == 0) ? 0 : sh[t - 1]);
    #pragma unroll
    for (int k = 0; k < 4; ++k) {
        int idx = base + k;
        if (idx < M) {
            row_ptr[idx] = run;
            dinv[idx] = rsqrtf((float)(c[k] + 1));
            run += c[k];
        }
    }
}

// counts doubles as the per-row cursor; one 4B scattered store per edge.
__global__ void fill2_kernel(const int* __restrict__ ei1, const int* __restrict__ ei2,
                             int E, int N, const int* __restrict__ row_ptr,
                             int* __restrict__ counts, int* __restrict__ col) {
    int i = blockIdx.x * blockDim.x + threadIdx.x;
    int src, dst;
    if (i < E)          { src = ei1[i];             dst = ei1[E + i]; }
    else if (i < 2 * E) { src = ei2[i - E] + N;     dst = ei2[E + (i - E)] + N; }
    else return;
    int p = atomicSub(&counts[dst], 1) - 1;
    col[row_ptr[dst] + p] = src;
}

// xs0[i] = x0[i] * dinv[i/64]; float4 per thread (stays within one node row).
__global__ void scale0_kernel(const float* __restrict__ f1, const float* __restrict__ f2,
                              const float* __restrict__ dinv, float* __restrict__ xs,
                              int n /* = N*64 */) {
    int i4 = (blockIdx.x * blockDim.x + threadIdx.x) * 4;
    if (i4 >= 2 * n) return;
    const float* src = (i4 < n) ? (f1 + i4) : (f2 + (i4 - n));
    float dv = dinv[i4 >> 6];
    float4 v = *(const float4*)src;
    v.x *= dv; v.y *= dv; v.z *= dv; v.w *= dv;
    *(float4*)(xs + i4) = v;
}

// Wave per node; lane = feature. PURE gather+add; out = sum * dinv[v].
__global__ void agg64_kernel(const float* __restrict__ xs, float* __restrict__ out,
                             const int* __restrict__ row_ptr, const int* __restrict__ col,
                             const float* __restrict__ dinv, int M) {
    int gt = blockIdx.x * blockDim.x + threadIdx.x;
    int v = gt >> 6;
    int lane = gt & 63;
    if (v >= M) return;
    float acc = xs[(size_t)v * 64 + lane];    // self-loop term (already *dinv[v])
    int s = row_ptr[v], e = row_ptr[v + 1];
    int i = s;
    for (; i + 4 <= e; i += 4) {
        int u0 = col[i], u1 = col[i + 1], u2 = col[i + 2], u3 = col[i + 3];
        float a0 = xs[(size_t)u0 * 64 + lane];
        float a1 = xs[(size_t)u1 * 64 + lane];
        float a2 = xs[(size_t)u2 * 64 + lane];
        float a3 = xs[(size_t)u3 * 64 + lane];
        acc += (a0 + a1) + (a2 + a3);
    }
    for (; i < e; ++i) acc += xs[(size_t)col[i] * 64 + lane];
    out[(size_t)v * 64 + lane] = acc * dinv[v];
}

// Dense: out[v][j] = relu(sum_k in[v][k]*W[k][j] + b[j]) * dinv[v]; grid-stride.
__global__ void gemm64s_kernel(const float* __restrict__ in, float* __restrict__ out,
                               const float* __restrict__ W, const float* __restrict__ b,
                               const float* __restrict__ dinv, int M, int num_waves) {
    __shared__ float Ws[64 * 64];
    for (int i = threadIdx.x; i < 64 * 64; i += blockDim.x) Ws[i] = W[i];
    __syncthreads();
    int lane = threadIdx.x & 63;
    int wid = (blockIdx.x * blockDim.x + threadIdx.x) >> 6;
    float bj = b[lane];
    for (int v = wid; v < M; v += num_waves) {
        float r = in[(size_t)v * 64 + lane];
        float acc = bj;
        #pragma unroll
        for (int k = 0; k < 64; ++k) acc += __shfl(r, k) * Ws[k * 64 + lane];
        out[(size_t)v * 64 + lane] = fmaxf(acc, 0.f) * dinv[v];
    }
}

// Dense: h3s = (relu(in@W2+b2)@W3) * dinv, 64->32; grid-stride waves.
__global__ void gemm64_32s_kernel(const float* __restrict__ in, float* __restrict__ out,
                                  const float* __restrict__ W2, const float* __restrict__ b2,
                                  const float* __restrict__ W3, const float* __restrict__ dinv,
                                  int M, int num_waves) {
    __shared__ float Ws2[64 * 64];
    __shared__ float Ws3[64 * 32];
    for (int i = threadIdx.x; i < 64 * 64; i += blockDim.x) Ws2[i] = W2[i];
    for (int i = threadIdx.x; i < 64 * 32; i += blockDim.x) Ws3[i] = W3[i];
    __syncthreads();
    int lane = threadIdx.x & 63;
    int j32 = lane & 31;
    int wid = (blockIdx.x * blockDim.x + threadIdx.x) >> 6;
    float bj = b2[lane];
    for (int v = wid; v < M; v += num_waves) {
        float r = in[(size_t)v * 64 + lane];
        float x2v = bj;
        #pragma unroll
        for (int k = 0; k < 64; ++k) x2v += __shfl(r, k) * Ws2[k * 64 + lane];
        x2v = fmaxf(x2v, 0.f);
        float h = 0.f;
        #pragma unroll
        for (int k = 0; k < 64; ++k) h += __shfl(x2v, k) * Ws3[k * 32 + j32];
        if (lane < 32) out[(size_t)v * 32 + lane] = h * dinv[v];
    }
}

// agg32: a3 = rowsum(h3s)*dinv + b; fused per-graph column sums.
__global__ void agg32_colsum_kernel(const float* __restrict__ hs, float* __restrict__ out,
                                    const int* __restrict__ row_ptr, const int* __restrict__ col,
                                    const float* __restrict__ dinv, const float* __restrict__ b,
                                    float* __restrict__ msum, int N, int halfgrid) {
    int g = (blockIdx.x >= halfgrid) ? 1 : 0;
    int bid = blockIdx.x - g * halfgrid;
    int t = threadIdx.x;
    int lane = t & 31;
    int hw = (bid * blockDim.x + t) >> 5;
    int nhw = (halfgrid * blockDim.x) >> 5;
    float bl = b[lane];
    float csum = 0.f;
    int base = g * N;
    for (int vv = hw; vv < N; vv += nhw) {
        int v = base + vv;
        float acc = hs[(size_t)v * 32 + lane];
        int s = row_ptr[v], e = row_ptr[v + 1];
        int i = s;
        for (; i + 4 <= e; i += 4) {
            int u0 = col[i], u1 = col[i + 1], u2 = col[i + 2], u3 = col[i + 3];
            float a0 = hs[(size_t)u0 * 32 + lane];
            float a1 = hs[(size_t)u1 * 32 + lane];
            float a2 = hs[(size_t)u2 * 32 + lane];
            float a3 = hs[(size_t)u3 * 32 + lane];
            acc += (a0 + a1) + (a2 + a3);
        }
        for (; i < e; ++i) acc += hs[(size_t)col[i] * 32 + lane];
        float o = acc * dinv[v] + bl;
        out[(size_t)v * 32 + lane] = o;
        csum += o;
    }
    __shared__ float sp[256];
    sp[t] = csum;
    __syncthreads();
    if (t < 32) {
        float s = 0.f;
        for (int w = 0; w < 8; ++w) s += sp[w * 32 + t];
        atomicAdd(&msum[g * 32 + t], s);
    }
}

// ctx[g*32+j] = tanh( sum_i (msum[g*32+i]/N) * W_att[i][j] ); one 64-thread block.
__global__ void ctx2_kernel(const float* __restrict__ msum, const float* __restrict__ W_att,
                            float* __restrict__ ctx, int N) {
    int t = threadIdx.x;
    if (t >= 64) return;
    int g = t >> 5, j = t & 31;
    float invN = 1.f / (float)N;
    float acc = 0.f;
    for (int i = 0; i < 32; ++i) acc += (msum[g * 32 + i] * invN) * W_att[i * 32 + j];
    ctx[g * 32 + j] = tanhf(acc);
}

// pooled[g*32+j] = sum_n sigmoid(a3[n].ctx_g) * a3[n][j]
__global__ void pool2_kernel(const float* __restrict__ a3, const float* __restrict__ ctx,
                             float* __restrict__ pooled, int N, int halfgrid) {
    int g = (blockIdx.x >= halfgrid) ? 1 : 0;
    int bid = blockIdx.x - g * halfgrid;
    int t = threadIdx.x;
    int j = t & 31;
    int hw = (bid * blockDim.x + t) >> 5;
    int nhw = (halfgrid * blockDim.x) >> 5;
    const float* base = a3 + (size_t)g * N * 32;
    float cj = ctx[g * 32 + j];
    float local = 0.f;
    for (int n = hw; n < N; n += nhw) {
        float v = base[(size_t)n * 32 + j];
        float d = v * cj;
        #pragma unroll
        for (int off = 16; off; off >>= 1) d += __shfl_xor(d, off);  // stays in 32-lane half
        float s = 1.f / (1.f + __expf(-d));
        local += s * v;
    }
    __shared__ float sp[256];
    sp[t] = local;
    __syncthreads();
    if (t < 32) {
        float s = 0.f;
        for (int w = 0; w < 8; ++w) s += sp[w * 32 + t];
        atomicAdd(&pooled[g * 32 + t], s);
    }
}

// NTN: out[k] = relu( sum_ij e1[i] W_tn[i,j,k] e2[j] + W_block[k].[e1;e2] + b_tn[k] )
__global__ void ntn_kernel(const float* __restrict__ p1, const float* __restrict__ p2,
                           const float* __restrict__ W_tn, const float* __restrict__ W_block,
                           const float* __restrict__ b_tn, float* __restrict__ out) {
    int k = threadIdx.x;
    if (k >= 16) return;
    float sc = 0.f;
    for (int i = 0; i < 32; ++i) {
        float e1 = p1[i];
        for (int j = 0; j < 32; ++j) sc += e1 * W_tn[i * 512 + j * 16 + k] * p2[j];
    }
    float bl = 0.f;
    for (int j = 0; j < 32; ++j)
        bl += W_block[k * 64 + j] * p1[j] + W_block[k * 64 + 32 + j] * p2[j];
    float v = sc + bl + b_tn[k];
    out[k] = v > 0.f ? v : 0.f;
}

extern "C" void kernel_launch(void* const* d_in, const int* in_sizes, int n_in,
                              void* d_out, int out_size, void* d_ws, size_t ws_size,
                              hipStream_t stream) {
    const float* f1     = (const float*)d_in[0];
    const int*   ei1    = (const int*)  d_in[1];
    const float* f2     = (const float*)d_in[2];
    const int*   ei2    = (const int*)  d_in[3];
    const float* W1     = (const float*)d_in[4];
    const float* b1     = (const float*)d_in[5];
    const float* W2     = (const float*)d_in[6];
    const float* b2     = (const float*)d_in[7];
    const float* W3     = (const float*)d_in[8];
    const float* b3     = (const float*)d_in[9];
    const float* W_att  = (const float*)d_in[10];
    const float* W_tn   = (const float*)d_in[11];
    const float* W_blk  = (const float*)d_in[12];
    const float* b_tn   = (const float*)d_in[13];

    int N = in_sizes[0] / 64;
    int E = in_sizes[1] / 2;
    int M = 2 * N;
    int E2 = 2 * E;

    char* ws = (char*)d_ws;
    size_t off = 0;
    auto alloc = [&](size_t bytes) -> void* {
        void* p = ws + off;
        off += (bytes + 511) & ~(size_t)511;
        return p;
    };
    float* bufA    = (float*)alloc((size_t)M * 64 * sizeof(float));  // xs0 -> xs1 -> h3s
    float* bufB    = (float*)alloc((size_t)M * 64 * sizeof(float));  // t1 -> t2 -> a3
    int*   col     = (int*)  alloc((size_t)E2 * sizeof(int));
    int*   row_ptr = (int*)  alloc((size_t)(M + 1) * sizeof(int));
    int*   counts  = (int*)  alloc((size_t)M * sizeof(int));
    float* dinv    = (float*)alloc((size_t)M * sizeof(float));
    int*   bsum    = (int*)  alloc(256 * sizeof(int));
    float* smalls  = (float*)alloc(256 * sizeof(float));
    float* msum   = smalls;        // [64]
    float* pooled = smalls + 64;   // [64]
    float* ctx    = smalls + 128;  // [64]

    hipMemsetAsync(smalls, 0, 256 * sizeof(float), stream);
    hipMemsetAsync(counts, 0, (size_t)M * sizeof(int), stream);

    int eb = (E2 + 255) / 256;
    int P  = (M + 1023) / 1024;

    // CSR build
    count2_kernel<<<eb, 256, 0, stream>>>(ei1, ei2, E, N, counts);
    scanA_kernel<<<P, 256, 0, stream>>>(counts, bsum, M);
    scanB_kernel<<<1, 256, 0, stream>>>(bsum, P, row_ptr, M);
    scanC_kernel<<<P, 256, 0, stream>>>(counts, bsum, row_ptr, dinv, M);
    fill2_kernel<<<eb, 256, 0, stream>>>(ei1, ei2, E, N, row_ptr, counts, col);

    // Pre-scaled input table
    int cvb = (M * 64 / 4 + 255) / 256;
    scale0_kernel<<<cvb, 256, 0, stream>>>(f1, f2, dinv, bufA, N * 64);

    // GCN stack
    int nb64 = (M * 64 + 255) / 256;       // wave-per-node
    const int GB = 1024;                   // dense gemm grid
    int num_waves = GB * (256 / 64);
    agg64_kernel<<<nb64, 256, 0, stream>>>(bufA, bufB, row_ptr, col, dinv, M);            // t1
    gemm64s_kernel<<<GB, 256, 0, stream>>>(bufB, bufA, W1, b1, dinv, M, num_waves);       // xs1
    agg64_kernel<<<nb64, 256, 0, stream>>>(bufA, bufB, row_ptr, col, dinv, M);            // t2
    gemm64_32s_kernel<<<GB, 256, 0, stream>>>(bufB, bufA, W2, b2, W3, dinv, M, num_waves);// h3s

    const int HG = 512;
    agg32_colsum_kernel<<<2 * HG, 256, 0, stream>>>(bufA, bufB, row_ptr, col, dinv, b3, msum, N, HG);

    ctx2_kernel<<<1, 64, 0, stream>>>(msum, W_att, ctx, N);
    pool2_kernel<<<2 * 256, 256, 0, stream>>>(bufB, ctx, pooled, N, 256);
    ntn_kernel<<<1, 64, 0, stream>>>(pooled, pooled + 32, W_tn, W_blk, b_tn, (float*)d_out);
}

// Round 6
// 529.245 us; speedup vs baseline: 1.8200x; 1.5174x over previous
//
#include <hip/hip_runtime.h>
#include <math.h>

// ---------------------------------------------------------------------------
// SimGNN forward on MI355X — combined-graph pipeline, MFMA dense GEMMs.
// M = 2N nodes (graph-2 ids offset +N). One CSR build, col = src only.
// Pre-scaled tables: (A x)[v] = dinv[v]*(xs[v] + sum_{u->v} xs[u]).
//   scale0 : xs0 = x0 * dinv                       [M,64] f32
//   agg64  : t1 = rowsum(xs0)*dinv                 [M,64] f16  (pure gather+add)
//   mfma1  : xs1 = relu(t1@W1+b1)*dinv             [M,64] f32  (MFMA 16x16x32 f16)
//   agg64  : t2 = rowsum(xs1)*dinv                 [M,64] f16
//   mfma2  : h3s = (relu(t2@W2+b2)@W3)*dinv        [M,32] f32  (2 chained MFMAs)
//   agg32  : a3 = rowsum(h3s)*dinv + b3, msum += colsum(a3)
//   ctx = tanh(msum/N @ W_att); pooled = a3^T sigmoid(a3 ctx); NTN -> 16 out
// R5 post-mortem: shfl-based GEMMs were LDS-pipe-bound (~450 us for 2 GFLOP).
// MFMA A-frags load straight from global f16 rows; W pre-packed to B-frag
// order (A/B slot maps are symmetric -> same-formula packing is
// permutation-invariant); C/D map col=lane&15, row=quad*4+reg (m89-verified).
// ---------------------------------------------------------------------------

typedef _Float16 f16x8 __attribute__((ext_vector_type(8)));
typedef float    f32x4 __attribute__((ext_vector_type(4)));

__global__ void count2_kernel(const int* __restrict__ ei1, const int* __restrict__ ei2,
                              int E, int N, int* __restrict__ counts) {
    int i = blockIdx.x * blockDim.x + threadIdx.x;
    if (i < E)          atomicAdd(&counts[ei1[E + i]], 1);
    else if (i < 2 * E) atomicAdd(&counts[ei2[E + (i - E)] + N], 1);
}

// ---- 3-phase scan over counts[M] -> row_ptr[M+1], dinv[M] ----
__global__ void scanA_kernel(const int* __restrict__ counts, int* __restrict__ bsum, int M) {
    __shared__ int sh[256];
    int t = threadIdx.x;
    int base = blockIdx.x * 1024 + t * 4;
    int s = 0;
    #pragma unroll
    for (int k = 0; k < 4; ++k) { int idx = base + k; if (idx < M) s += counts[idx]; }
    sh[t] = s;
    __syncthreads();
    for (int off = 128; off; off >>= 1) {
        if (t < off) sh[t] += sh[t + off];
        __syncthreads();
    }
    if (t == 0) bsum[blockIdx.x] = sh[0];
}

__global__ void scanB_kernel(int* __restrict__ bsum, int P, int* __restrict__ row_ptr, int M) {
    __shared__ int sh[256];
    int t = threadIdx.x;
    sh[t] = (t < P) ? bsum[t] : 0;
    __syncthreads();
    for (int off = 1; off < 256; off <<= 1) {
        int v = (t >= off) ? sh[t - off] : 0;
        __syncthreads();
        sh[t] += v;
        __syncthreads();
    }
    if (t < P) bsum[t] = (t == 0) ? 0 : sh[t - 1];
    if (t == 255) row_ptr[M] = sh[255];
}

__global__ void scanC_kernel(const int* __restrict__ counts, const int* __restrict__ bsum,
                             int* __restrict__ row_ptr, float* __restrict__ dinv, int M) {
    __shared__ int sh[256];
    int t = threadIdx.x;
    int base = blockIdx.x * 1024 + t * 4;
    int c[4];
    int s = 0;
    #pragma unroll
    for (int k = 0; k < 4; ++k) { int idx = base + k; c[k] = (idx < M) ? counts[idx] : 0; s += c[k]; }
    sh[t] = s;
    __syncthreads();
    for (int off = 1; off < 256; off <<= 1) {
        int v = (t >= off) ? sh[t - off] : 0;
        __syncthreads();
        sh[t] += v;
        __syncthreads();
    }
    int run = bsum[blockIdx.x] + ((t == 0) ? 0 : sh[t - 1]);
    #pragma unroll
    for (int k = 0; k < 4; ++k) {
        int idx = base + k;
        if (idx < M) {
            row_ptr[idx] = run;
            dinv[idx] = rsqrtf((float)(c[k] + 1));
            run += c[k];
        }
    }
}

__global__ void fill2_kernel(const int* __restrict__ ei1, const int* __restrict__ ei2,
                             int E, int N, const int* __restrict__ row_ptr,
                             int* __restrict__ counts, int* __restrict__ col) {
    int i = blockIdx.x * blockDim.x + threadIdx.x;
    int src, dst;
    if (i < E)          { src = ei1[i];             dst = ei1[E + i]; }
    else if (i < 2 * E) { src = ei2[i - E] + N;     dst = ei2[E + (i - E)] + N; }
    else return;
    int p = atomicSub(&counts[dst], 1) - 1;
    col[row_ptr[dst] + p] = src;
}

// xs0[i] = x0[i] * dinv[i/64]; float4 per thread.
__global__ void scale0_kernel(const float* __restrict__ f1, const float* __restrict__ f2,
                              const float* __restrict__ dinv, float* __restrict__ xs,
                              int n /* = N*64 */) {
    int i4 = (blockIdx.x * blockDim.x + threadIdx.x) * 4;
    if (i4 >= 2 * n) return;
    const float* src = (i4 < n) ? (f1 + i4) : (f2 + (i4 - n));
    float dv = dinv[i4 >> 6];
    float4 v = *(const float4*)src;
    v.x *= dv; v.y *= dv; v.z *= dv; v.w *= dv;
    *(float4*)(xs + i4) = v;
}

// Pack W1,W2 (64x64) and W3 (64x32) into MFMA B-fragment order, f16.
// Frag slot formula (must match A-load): k = s*32 + (lane>>4)*8 + j.
// pk layout: [0..4095]=W1, [4096..8191]=W2, [8192..10239]=W3.
__global__ void packW_kernel(const float* __restrict__ W1, const float* __restrict__ W2,
                             const float* __restrict__ W3, _Float16* __restrict__ pk) {
    int t = blockIdx.x * blockDim.x + threadIdx.x;
    if (t < 8192) {
        const float* W = (t < 4096) ? W1 : W2;
        int idx = t & 4095;
        int j = idx & 7, slot = idx >> 3;
        int lane = slot & 63, s = (slot >> 6) & 1, ct = slot >> 7;
        int k = s * 32 + ((lane >> 4) << 3) + j;
        int n = ct * 16 + (lane & 15);
        pk[t] = (_Float16)W[k * 64 + n];
    } else if (t < 10240) {
        int idx = t - 8192;
        int j = idx & 7, slot = idx >> 3;
        int lane = slot & 63, s = (slot >> 6) & 1, ct = slot >> 7;  // ct in 0..1
        int k = s * 32 + ((lane >> 4) << 3) + j;
        int n = ct * 16 + (lane & 15);
        pk[t] = (_Float16)W3[k * 32 + n];
    }
}

// Wave per node; PURE gather+add on fp32 table; f16 output row.
__global__ void agg64_kernel(const float* __restrict__ xs, _Float16* __restrict__ out,
                             const int* __restrict__ row_ptr, const int* __restrict__ col,
                             const float* __restrict__ dinv, int M) {
    int gt = blockIdx.x * blockDim.x + threadIdx.x;
    int v = gt >> 6;
    int lane = gt & 63;
    if (v >= M) return;
    float acc = xs[(size_t)v * 64 + lane];
    int s = row_ptr[v], e = row_ptr[v + 1];
    int i = s;
    for (; i + 4 <= e; i += 4) {
        int u0 = col[i], u1 = col[i + 1], u2 = col[i + 2], u3 = col[i + 3];
        float a0 = xs[(size_t)u0 * 64 + lane];
        float a1 = xs[(size_t)u1 * 64 + lane];
        float a2 = xs[(size_t)u2 * 64 + lane];
        float a3 = xs[(size_t)u3 * 64 + lane];
        acc += (a0 + a1) + (a2 + a3);
    }
    for (; i < e; ++i) acc += xs[(size_t)col[i] * 64 + lane];
    out[(size_t)v * 64 + lane] = (_Float16)(acc * dinv[v]);
}

// MFMA GEMM: xs1 = relu(t@W1+b1)*dinv. Wave = 16 rows x 64 cols, K=64.
__global__ void mfma_gemm64_kernel(const _Float16* __restrict__ tA, float* __restrict__ out,
                                   const _Float16* __restrict__ pk, const float* __restrict__ b1,
                                   const float* __restrict__ dinv, int M) {
    int wave = (blockIdx.x * blockDim.x + threadIdx.x) >> 6;
    int lane = threadIdx.x & 63;
    int base = wave * 16;
    if (base >= M) return;
    int l15 = lane & 15, q = lane >> 4;
    const f16x8* arow = (const f16x8*)(tA + (size_t)(base + l15) * 64);
    f16x8 a0 = arow[q];        // k = q*8..q*8+7
    f16x8 a1 = arow[q + 4];    // k = 32 + q*8..
    const f16x8* bp = (const f16x8*)pk;
    f32x4 acc[4];
    #pragma unroll
    for (int ct = 0; ct < 4; ++ct) {
        f32x4 c = {0.f, 0.f, 0.f, 0.f};
        c = __builtin_amdgcn_mfma_f32_16x16x32_f16(a0, bp[(ct * 2 + 0) * 64 + lane], c, 0, 0, 0);
        c = __builtin_amdgcn_mfma_f32_16x16x32_f16(a1, bp[(ct * 2 + 1) * 64 + lane], c, 0, 0, 0);
        acc[ct] = c;
    }
    float dv[4];
    #pragma unroll
    for (int r = 0; r < 4; ++r) dv[r] = dinv[base + q * 4 + r];
    #pragma unroll
    for (int ct = 0; ct < 4; ++ct) {
        float bj = b1[ct * 16 + l15];
        #pragma unroll
        for (int r = 0; r < 4; ++r)
            out[(size_t)(base + q * 4 + r) * 64 + ct * 16 + l15] = fmaxf(acc[ct][r] + bj, 0.f) * dv[r];
    }
}

// MFMA double GEMM: h3s = (relu(t@W2+b2)@W3)*dinv. x2 transposed via per-wave LDS.
__global__ void mfma_gemm64_32_kernel(const _Float16* __restrict__ tA, float* __restrict__ out,
                                      const _Float16* __restrict__ pk2, const _Float16* __restrict__ pk3,
                                      const float* __restrict__ b2, const float* __restrict__ dinv,
                                      int M) {
    __shared__ _Float16 xl[4][16][72];   // 72: 144B row stride, 16B-aligned
    int wv = threadIdx.x >> 6;
    int wave = (blockIdx.x * blockDim.x + threadIdx.x) >> 6;
    int lane = threadIdx.x & 63;
    int base = wave * 16;
    if (base >= M) return;
    int l15 = lane & 15, q = lane >> 4;
    const f16x8* arow = (const f16x8*)(tA + (size_t)(base + l15) * 64);
    f16x8 a0 = arow[q];
    f16x8 a1 = arow[q + 4];
    const f16x8* bp2 = (const f16x8*)pk2;
    #pragma unroll
    for (int ct = 0; ct < 4; ++ct) {
        f32x4 c = {0.f, 0.f, 0.f, 0.f};
        c = __builtin_amdgcn_mfma_f32_16x16x32_f16(a0, bp2[(ct * 2 + 0) * 64 + lane], c, 0, 0, 0);
        c = __builtin_amdgcn_mfma_f32_16x16x32_f16(a1, bp2[(ct * 2 + 1) * 64 + lane], c, 0, 0, 0);
        float bj = b2[ct * 16 + l15];
        #pragma unroll
        for (int r = 0; r < 4; ++r)
            xl[wv][q * 4 + r][ct * 16 + l15] = (_Float16)fmaxf(c[r] + bj, 0.f);
    }
    // Read x2 back in A-operand layout (same wave; compiler inserts lgkmcnt wait).
    const f16x8* xr = (const f16x8*)(&xl[wv][l15][0]);
    f16x8 e0 = xr[q];
    f16x8 e1 = xr[q + 4];
    const f16x8* bp3 = (const f16x8*)pk3;
    float dv[4];
    #pragma unroll
    for (int r = 0; r < 4; ++r) dv[r] = dinv[base + q * 4 + r];
    #pragma unroll
    for (int ct = 0; ct < 2; ++ct) {
        f32x4 c = {0.f, 0.f, 0.f, 0.f};
        c = __builtin_amdgcn_mfma_f32_16x16x32_f16(e0, bp3[(ct * 2 + 0) * 64 + lane], c, 0, 0, 0);
        c = __builtin_amdgcn_mfma_f32_16x16x32_f16(e1, bp3[(ct * 2 + 1) * 64 + lane], c, 0, 0, 0);
        #pragma unroll
        for (int r = 0; r < 4; ++r)
            out[(size_t)(base + q * 4 + r) * 32 + ct * 16 + l15] = c[r] * dv[r];
    }
}

// agg32: a3 = rowsum(h3s)*dinv + b; fused per-graph column sums.
__global__ void agg32_colsum_kernel(const float* __restrict__ hs, float* __restrict__ out,
                                    const int* __restrict__ row_ptr, const int* __restrict__ col,
                                    const float* __restrict__ dinv, const float* __restrict__ b,
                                    float* __restrict__ msum, int N, int halfgrid) {
    int g = (blockIdx.x >= halfgrid) ? 1 : 0;
    int bid = blockIdx.x - g * halfgrid;
    int t = threadIdx.x;
    int lane = t & 31;
    int hw = (bid * blockDim.x + t) >> 5;
    int nhw = (halfgrid * blockDim.x) >> 5;
    float bl = b[lane];
    float csum = 0.f;
    int base = g * N;
    for (int vv = hw; vv < N; vv += nhw) {
        int v = base + vv;
        float acc = hs[(size_t)v * 32 + lane];
        int s = row_ptr[v], e = row_ptr[v + 1];
        int i = s;
        for (; i + 4 <= e; i += 4) {
            int u0 = col[i], u1 = col[i + 1], u2 = col[i + 2], u3 = col[i + 3];
            float a0 = hs[(size_t)u0 * 32 + lane];
            float a1 = hs[(size_t)u1 * 32 + lane];
            float a2 = hs[(size_t)u2 * 32 + lane];
            float a3 = hs[(size_t)u3 * 32 + lane];
            acc += (a0 + a1) + (a2 + a3);
        }
        for (; i < e; ++i) acc += hs[(size_t)col[i] * 32 + lane];
        float o = acc * dinv[v] + bl;
        out[(size_t)v * 32 + lane] = o;
        csum += o;
    }
    __shared__ float sp[256];
    sp[t] = csum;
    __syncthreads();
    if (t < 32) {
        float s = 0.f;
        for (int w = 0; w < 8; ++w) s += sp[w * 32 + t];
        atomicAdd(&msum[g * 32 + t], s);
    }
}

__global__ void ctx2_kernel(const float* __restrict__ msum, const float* __restrict__ W_att,
                            float* __restrict__ ctx, int N) {
    int t = threadIdx.x;
    if (t >= 64) return;
    int g = t >> 5, j = t & 31;
    float invN = 1.f / (float)N;
    float acc = 0.f;
    for (int i = 0; i < 32; ++i) acc += (msum[g * 32 + i] * invN) * W_att[i * 32 + j];
    ctx[g * 32 + j] = tanhf(acc);
}

__global__ void pool2_kernel(const float* __restrict__ a3, const float* __restrict__ ctx,
                             float* __restrict__ pooled, int N, int halfgrid) {
    int g = (blockIdx.x >= halfgrid) ? 1 : 0;
    int bid = blockIdx.x - g * halfgrid;
    int t = threadIdx.x;
    int j = t & 31;
    int hw = (bid * blockDim.x + t) >> 5;
    int nhw = (halfgrid * blockDim.x) >> 5;
    const float* base = a3 + (size_t)g * N * 32;
    float cj = ctx[g * 32 + j];
    float local = 0.f;
    for (int n = hw; n < N; n += nhw) {
        float v = base[(size_t)n * 32 + j];
        float d = v * cj;
        #pragma unroll
        for (int off = 16; off; off >>= 1) d += __shfl_xor(d, off);
        float s = 1.f / (1.f + __expf(-d));
        local += s * v;
    }
    __shared__ float sp[256];
    sp[t] = local;
    __syncthreads();
    if (t < 32) {
        float s = 0.f;
        for (int w = 0; w < 8; ++w) s += sp[w * 32 + t];
        atomicAdd(&pooled[g * 32 + t], s);
    }
}

__global__ void ntn_kernel(const float* __restrict__ p1, const float* __restrict__ p2,
                           const float* __restrict__ W_tn, const float* __restrict__ W_block,
                           const float* __restrict__ b_tn, float* __restrict__ out) {
    int k = threadIdx.x;
    if (k >= 16) return;
    float sc = 0.f;
    for (int i = 0; i < 32; ++i) {
        float e1 = p1[i];
        for (int j = 0; j < 32; ++j) sc += e1 * W_tn[i * 512 + j * 16 + k] * p2[j];
    }
    float bl = 0.f;
    for (int j = 0; j < 32; ++j)
        bl += W_block[k * 64 + j] * p1[j] + W_block[k * 64 + 32 + j] * p2[j];
    float v = sc + bl + b_tn[k];
    out[k] = v > 0.f ? v : 0.f;
}

extern "C" void kernel_launch(void* const* d_in, const int* in_sizes, int n_in,
                              void* d_out, int out_size, void* d_ws, size_t ws_size,
                              hipStream_t stream) {
    const float* f1     = (const float*)d_in[0];
    const int*   ei1    = (const int*)  d_in[1];
    const float* f2     = (const float*)d_in[2];
    const int*   ei2    = (const int*)  d_in[3];
    const float* W1     = (const float*)d_in[4];
    const float* b1     = (const float*)d_in[5];
    const float* W2     = (const float*)d_in[6];
    const float* b2     = (const float*)d_in[7];
    const float* W3     = (const float*)d_in[8];
    const float* b3     = (const float*)d_in[9];
    const float* W_att  = (const float*)d_in[10];
    const float* W_tn   = (const float*)d_in[11];
    const float* W_blk  = (const float*)d_in[12];
    const float* b_tn   = (const float*)d_in[13];

    int N = in_sizes[0] / 64;
    int E = in_sizes[1] / 2;
    int M = 2 * N;
    int E2 = 2 * E;

    char* ws = (char*)d_ws;
    size_t off = 0;
    auto alloc = [&](size_t bytes) -> void* {
        void* p = ws + off;
        off += (bytes + 511) & ~(size_t)511;
        return p;
    };
    float*     xsA     = (float*)    alloc((size_t)M * 64 * sizeof(float));   // xs0 -> h3s -> (reuse)
    float*     xsB     = (float*)    alloc((size_t)M * 64 * sizeof(float));   // xs1 -> a3
    _Float16*  tH      = (_Float16*) alloc((size_t)M * 64 * sizeof(_Float16)); // t1 / t2 (f16)
    int*       col     = (int*)      alloc((size_t)E2 * sizeof(int));
    int*       row_ptr = (int*)      alloc((size_t)(M + 1) * sizeof(int));
    int*       counts  = (int*)      alloc((size_t)M * sizeof(int));
    float*     dinv    = (float*)    alloc((size_t)M * sizeof(float));
    int*       bsum    = (int*)      alloc(256 * sizeof(int));
    _Float16*  pk      = (_Float16*) alloc(10240 * sizeof(_Float16));
    float*     smalls  = (float*)    alloc(256 * sizeof(float));
    float* msum   = smalls;        // [64]
    float* pooled = smalls + 64;   // [64]
    float* ctx    = smalls + 128;  // [64]
    _Float16* pk1 = pk, *pk2 = pk + 4096, *pk3 = pk + 8192;

    hipMemsetAsync(smalls, 0, 256 * sizeof(float), stream);
    hipMemsetAsync(counts, 0, (size_t)M * sizeof(int), stream);

    int eb = (E2 + 255) / 256;
    int P  = (M + 1023) / 1024;

    // CSR build
    count2_kernel<<<eb, 256, 0, stream>>>(ei1, ei2, E, N, counts);
    scanA_kernel<<<P, 256, 0, stream>>>(counts, bsum, M);
    scanB_kernel<<<1, 256, 0, stream>>>(bsum, P, row_ptr, M);
    scanC_kernel<<<P, 256, 0, stream>>>(counts, bsum, row_ptr, dinv, M);
    fill2_kernel<<<eb, 256, 0, stream>>>(ei1, ei2, E, N, row_ptr, counts, col);

    // Weight packing + pre-scaled input table
    packW_kernel<<<40, 256, 0, stream>>>(W1, W2, W3, pk);
    int cvb = (M * 64 / 4 + 255) / 256;
    scale0_kernel<<<cvb, 256, 0, stream>>>(f1, f2, dinv, xsA, N * 64);

    // GCN stack
    int nb64 = (M * 64 + 255) / 256;             // wave-per-node agg
    int gw   = ((M / 16) + 3) / 4;               // MFMA: 4 waves/block, 16 rows/wave
    agg64_kernel<<<nb64, 256, 0, stream>>>(xsA, tH, row_ptr, col, dinv, M);               // t1 (f16)
    mfma_gemm64_kernel<<<gw, 256, 0, stream>>>(tH, xsB, pk1, b1, dinv, M);                // xs1
    agg64_kernel<<<nb64, 256, 0, stream>>>(xsB, tH, row_ptr, col, dinv, M);               // t2 (f16)
    mfma_gemm64_32_kernel<<<gw, 256, 0, stream>>>(tH, xsA, pk2, pk3, b2, dinv, M);        // h3s

    const int HG = 512;
    agg32_colsum_kernel<<<2 * HG, 256, 0, stream>>>(xsA, xsB, row_ptr, col, dinv, b3, msum, N, HG);

    ctx2_kernel<<<1, 64, 0, stream>>>(msum, W_att, ctx, N);
    pool2_kernel<<<2 * 256, 256, 0, stream>>>(xsB, ctx, pooled, N, 256);
    ntn_kernel<<<1, 64, 0, stream>>>(pooled, pooled + 32, W_tn, W_blk, b_tn, (float*)d_out);
}

// Round 7
// 488.690 us; speedup vs baseline: 1.9710x; 1.0830x over previous
//
#include <hip/hip_runtime.h>
#include <math.h>

// ---------------------------------------------------------------------------
// SimGNN forward on MI355X — combined-graph pipeline, MFMA dense GEMMs,
// f16 gather tables, XCD-sliced CSR fill.
// M = 2N nodes (graph-2 ids offset +N). One CSR build, col = src only.
// Pre-scaled tables: (A x)[v] = dinv[v]*(xs[v] + sum_{u->v} xs[u]).
//   scale0 : xs0 = f16(x0 * dinv)                  [M,64] f16
//   agg64  : t1 = rowsum(xs0)*dinv                 [M,64] f16  (pure gather+add)
//   mfma1  : xs1 = f16(relu(t1@W1+b1)*dinv)        [M,64] f16  (MFMA 16x16x32)
//   agg64  : t2 = rowsum(xs1)*dinv                 [M,64] f16
//   mfma2  : h3s = f16((relu(t2@W2+b2)@W3)*dinv)   [M,32] f16  (64B rows = 1 line)
//   agg32  : a3 = rowsum(h3s)*dinv + b3 (f32), msum += colsum(a3)
//   ctx = tanh(msum/N @ W_att); pooled = a3^T sigmoid(a3 ctx); NTN -> 16 out
// R6 post-mortem: fill2 write-allocate thrash (111 MB for 6.4 MB payload) ->
// fixed by dst-slicing (8 slices, blockIdx%8 XCD-affine, L2-resident region).
// ---------------------------------------------------------------------------

typedef _Float16 f16x8 __attribute__((ext_vector_type(8)));
typedef _Float16 f16x4 __attribute__((ext_vector_type(4)));
typedef float    f32x4 __attribute__((ext_vector_type(4)));

__global__ void count2_kernel(const int* __restrict__ ei1, const int* __restrict__ ei2,
                              int E, int N, int* __restrict__ counts) {
    int i = blockIdx.x * blockDim.x + threadIdx.x;
    if (i < E)          atomicAdd(&counts[ei1[E + i]], 1);
    else if (i < 2 * E) atomicAdd(&counts[ei2[E + (i - E)] + N], 1);
}

// ---- 3-phase scan over counts[M] -> row_ptr[M+1], dinv[M] ----
__global__ void scanA_kernel(const int* __restrict__ counts, int* __restrict__ bsum, int M) {
    __shared__ int sh[256];
    int t = threadIdx.x;
    int base = blockIdx.x * 1024 + t * 4;
    int s = 0;
    #pragma unroll
    for (int k = 0; k < 4; ++k) { int idx = base + k; if (idx < M) s += counts[idx]; }
    sh[t] = s;
    __syncthreads();
    for (int off = 128; off; off >>= 1) {
        if (t < off) sh[t] += sh[t + off];
        __syncthreads();
    }
    if (t == 0) bsum[blockIdx.x] = sh[0];
}

__global__ void scanB_kernel(int* __restrict__ bsum, int P, int* __restrict__ row_ptr, int M) {
    __shared__ int sh[256];
    int t = threadIdx.x;
    sh[t] = (t < P) ? bsum[t] : 0;
    __syncthreads();
    for (int off = 1; off < 256; off <<= 1) {
        int v = (t >= off) ? sh[t - off] : 0;
        __syncthreads();
        sh[t] += v;
        __syncthreads();
    }
    if (t < P) bsum[t] = (t == 0) ? 0 : sh[t - 1];
    if (t == 255) row_ptr[M] = sh[255];
}

__global__ void scanC_kernel(const int* __restrict__ counts, const int* __restrict__ bsum,
                             int* __restrict__ row_ptr, float* __restrict__ dinv, int M) {
    __shared__ int sh[256];
    int t = threadIdx.x;
    int base = blockIdx.x * 1024 + t * 4;
    int c[4];
    int s = 0;
    #pragma unroll
    for (int k = 0; k < 4; ++k) { int idx = base + k; c[k] = (idx < M) ? counts[idx] : 0; s += c[k]; }
    sh[t] = s;
    __syncthreads();
    for (int off = 1; off < 256; off <<= 1) {
        int v = (t >= off) ? sh[t - off] : 0;
        __syncthreads();
        sh[t] += v;
        __syncthreads();
    }
    int run = bsum[blockIdx.x] + ((t == 0) ? 0 : sh[t - 1]);
    #pragma unroll
    for (int k = 0; k < 4; ++k) {
        int idx = base + k;
        if (idx < M) {
            row_ptr[idx] = run;
            dinv[idx] = rsqrtf((float)(c[k] + 1));
            run += c[k];
        }
    }
}

// XCD-sliced fill: block b handles dst slice b%8 (L2-resident col region per
// slice; blockIdx%8 is the XCD-affinity heuristic — perf-only, not correctness).
__global__ void fill2_kernel(const int* __restrict__ ei1, const int* __restrict__ ei2,
                             int E, int N, const int* __restrict__ row_ptr,
                             int* __restrict__ counts, int* __restrict__ col,
                             int blocks_per_slice) {
    int M = 2 * N;
    int ns = (M + 7) >> 3;
    int slice = blockIdx.x & 7;
    int sb    = blockIdx.x >> 3;
    int lo = slice * ns;
    int hi = lo + ns; if (hi > M) hi = M;
    int stride = blocks_per_slice * blockDim.x;
    int E2 = 2 * E;
    for (int i = sb * blockDim.x + threadIdx.x; i < E2; i += stride) {
        int src, dst;
        if (i < E) { src = ei1[i];         dst = ei1[E + i]; }
        else       { src = ei2[i - E] + N; dst = ei2[E + (i - E)] + N; }
        if (dst < lo || dst >= hi) continue;
        int p = atomicSub(&counts[dst], 1) - 1;
        col[row_ptr[dst] + p] = src;
    }
}

// xs0[i] = f16(x0[i] * dinv[i/64]); 4 elements per thread.
__global__ void scale0_kernel(const float* __restrict__ f1, const float* __restrict__ f2,
                              const float* __restrict__ dinv, _Float16* __restrict__ xs,
                              int n /* = N*64 */) {
    int i4 = (blockIdx.x * blockDim.x + threadIdx.x) * 4;
    if (i4 >= 2 * n) return;
    const float* src = (i4 < n) ? (f1 + i4) : (f2 + (i4 - n));
    float dv = dinv[i4 >> 6];
    float4 v = *(const float4*)src;
    f16x4 o = { (_Float16)(v.x * dv), (_Float16)(v.y * dv),
                (_Float16)(v.z * dv), (_Float16)(v.w * dv) };
    *(f16x4*)(xs + i4) = o;
}

// Pack W1,W2 (64x64) and W3 (64x32) into MFMA B-fragment order, f16.
// Frag slot formula (must match A-load): k = s*32 + (lane>>4)*8 + j.
__global__ void packW_kernel(const float* __restrict__ W1, const float* __restrict__ W2,
                             const float* __restrict__ W3, _Float16* __restrict__ pk) {
    int t = blockIdx.x * blockDim.x + threadIdx.x;
    if (t < 8192) {
        const float* W = (t < 4096) ? W1 : W2;
        int idx = t & 4095;
        int j = idx & 7, slot = idx >> 3;
        int lane = slot & 63, s = (slot >> 6) & 1, ct = slot >> 7;
        int k = s * 32 + ((lane >> 4) << 3) + j;
        int n = ct * 16 + (lane & 15);
        pk[t] = (_Float16)W[k * 64 + n];
    } else if (t < 10240) {
        int idx = t - 8192;
        int j = idx & 7, slot = idx >> 3;
        int lane = slot & 63, s = (slot >> 6) & 1, ct = slot >> 7;  // ct in 0..1
        int k = s * 32 + ((lane >> 4) << 3) + j;
        int n = ct * 16 + (lane & 15);
        pk[t] = (_Float16)W3[k * 32 + n];
    }
}

// Wave per node; PURE gather+add on f16 table (128B rows); f16 output row.
__global__ void agg64_kernel(const _Float16* __restrict__ xs, _Float16* __restrict__ out,
                             const int* __restrict__ row_ptr, const int* __restrict__ col,
                             const float* __restrict__ dinv, int M) {
    int gt = blockIdx.x * blockDim.x + threadIdx.x;
    int v = gt >> 6;
    int lane = gt & 63;
    if (v >= M) return;
    float acc = (float)xs[(size_t)v * 64 + lane];
    int s = row_ptr[v], e = row_ptr[v + 1];
    int i = s;
    for (; i + 4 <= e; i += 4) {
        int u0 = col[i], u1 = col[i + 1], u2 = col[i + 2], u3 = col[i + 3];
        float a0 = (float)xs[(size_t)u0 * 64 + lane];
        float a1 = (float)xs[(size_t)u1 * 64 + lane];
        float a2 = (float)xs[(size_t)u2 * 64 + lane];
        float a3 = (float)xs[(size_t)u3 * 64 + lane];
        acc += (a0 + a1) + (a2 + a3);
    }
    for (; i < e; ++i) acc += (float)xs[(size_t)col[i] * 64 + lane];
    out[(size_t)v * 64 + lane] = (_Float16)(acc * dinv[v]);
}

// MFMA GEMM: xs1 = f16(relu(t@W1+b1)*dinv). Wave = 16 rows x 64 cols, K=64.
__global__ void mfma_gemm64_kernel(const _Float16* __restrict__ tA, _Float16* __restrict__ out,
                                   const _Float16* __restrict__ pk, const float* __restrict__ b1,
                                   const float* __restrict__ dinv, int M) {
    int wave = (blockIdx.x * blockDim.x + threadIdx.x) >> 6;
    int lane = threadIdx.x & 63;
    int base = wave * 16;
    if (base >= M) return;
    int l15 = lane & 15, q = lane >> 4;
    const f16x8* arow = (const f16x8*)(tA + (size_t)(base + l15) * 64);
    f16x8 a0 = arow[q];        // k = q*8..q*8+7
    f16x8 a1 = arow[q + 4];    // k = 32 + q*8..
    const f16x8* bp = (const f16x8*)pk;
    f32x4 acc[4];
    #pragma unroll
    for (int ct = 0; ct < 4; ++ct) {
        f32x4 c = {0.f, 0.f, 0.f, 0.f};
        c = __builtin_amdgcn_mfma_f32_16x16x32_f16(a0, bp[(ct * 2 + 0) * 64 + lane], c, 0, 0, 0);
        c = __builtin_amdgcn_mfma_f32_16x16x32_f16(a1, bp[(ct * 2 + 1) * 64 + lane], c, 0, 0, 0);
        acc[ct] = c;
    }
    float dv[4];
    #pragma unroll
    for (int r = 0; r < 4; ++r) dv[r] = dinv[base + q * 4 + r];
    #pragma unroll
    for (int ct = 0; ct < 4; ++ct) {
        float bj = b1[ct * 16 + l15];
        #pragma unroll
        for (int r = 0; r < 4; ++r)
            out[(size_t)(base + q * 4 + r) * 64 + ct * 16 + l15] =
                (_Float16)(fmaxf(acc[ct][r] + bj, 0.f) * dv[r]);
    }
}

// MFMA double GEMM: h3s = f16((relu(t@W2+b2)@W3)*dinv). LDS transpose between.
__global__ void mfma_gemm64_32_kernel(const _Float16* __restrict__ tA, _Float16* __restrict__ out,
                                      const _Float16* __restrict__ pk2, const _Float16* __restrict__ pk3,
                                      const float* __restrict__ b2, const float* __restrict__ dinv,
                                      int M) {
    __shared__ _Float16 xl[4][16][72];   // 144B row stride, 16B-aligned
    int wv = threadIdx.x >> 6;
    int wave = (blockIdx.x * blockDim.x + threadIdx.x) >> 6;
    int lane = threadIdx.x & 63;
    int base = wave * 16;
    if (base >= M) return;
    int l15 = lane & 15, q = lane >> 4;
    const f16x8* arow = (const f16x8*)(tA + (size_t)(base + l15) * 64);
    f16x8 a0 = arow[q];
    f16x8 a1 = arow[q + 4];
    const f16x8* bp2 = (const f16x8*)pk2;
    #pragma unroll
    for (int ct = 0; ct < 4; ++ct) {
        f32x4 c = {0.f, 0.f, 0.f, 0.f};
        c = __builtin_amdgcn_mfma_f32_16x16x32_f16(a0, bp2[(ct * 2 + 0) * 64 + lane], c, 0, 0, 0);
        c = __builtin_amdgcn_mfma_f32_16x16x32_f16(a1, bp2[(ct * 2 + 1) * 64 + lane], c, 0, 0, 0);
        float bj = b2[ct * 16 + l15];
        #pragma unroll
        for (int r = 0; r < 4; ++r)
            xl[wv][q * 4 + r][ct * 16 + l15] = (_Float16)fmaxf(c[r] + bj, 0.f);
    }
    const f16x8* xr = (const f16x8*)(&xl[wv][l15][0]);
    f16x8 e0 = xr[q];
    f16x8 e1 = xr[q + 4];
    const f16x8* bp3 = (const f16x8*)pk3;
    float dv[4];
    #pragma unroll
    for (int r = 0; r < 4; ++r) dv[r] = dinv[base + q * 4 + r];
    #pragma unroll
    for (int ct = 0; ct < 2; ++ct) {
        f32x4 c = {0.f, 0.f, 0.f, 0.f};
        c = __builtin_amdgcn_mfma_f32_16x16x32_f16(e0, bp3[(ct * 2 + 0) * 64 + lane], c, 0, 0, 0);
        c = __builtin_amdgcn_mfma_f32_16x16x32_f16(e1, bp3[(ct * 2 + 1) * 64 + lane], c, 0, 0, 0);
        #pragma unroll
        for (int r = 0; r < 4; ++r)
            out[(size_t)(base + q * 4 + r) * 32 + ct * 16 + l15] = (_Float16)(c[r] * dv[r]);
    }
}

// agg32: a3 = rowsum(h3s)*dinv + b (f32 out); fused per-graph column sums.
// h3s rows are 64B = exactly one cache line per gather.
__global__ void agg32_colsum_kernel(const _Float16* __restrict__ hs, float* __restrict__ out,
                                    const int* __restrict__ row_ptr, const int* __restrict__ col,
                                    const float* __restrict__ dinv, const float* __restrict__ b,
                                    float* __restrict__ msum, int N, int halfgrid) {
    int g = (blockIdx.x >= halfgrid) ? 1 : 0;
    int bid = blockIdx.x - g * halfgrid;
    int t = threadIdx.x;
    int lane = t & 31;
    int hw = (bid * blockDim.x + t) >> 5;
    int nhw = (halfgrid * blockDim.x) >> 5;
    float bl = b[lane];
    float csum = 0.f;
    int base = g * N;
    for (int vv = hw; vv < N; vv += nhw) {
        int v = base + vv;
        float acc = (float)hs[(size_t)v * 32 + lane];
        int s = row_ptr[v], e = row_ptr[v + 1];
        int i = s;
        for (; i + 4 <= e; i += 4) {
            int u0 = col[i], u1 = col[i + 1], u2 = col[i + 2], u3 = col[i + 3];
            float a0 = (float)hs[(size_t)u0 * 32 + lane];
            float a1 = (float)hs[(size_t)u1 * 32 + lane];
            float a2 = (float)hs[(size_t)u2 * 32 + lane];
            float a3 = (float)hs[(size_t)u3 * 32 + lane];
            acc += (a0 + a1) + (a2 + a3);
        }
        for (; i < e; ++i) acc += (float)hs[(size_t)col[i] * 32 + lane];
        float o = acc * dinv[v] + bl;
        out[(size_t)v * 32 + lane] = o;
        csum += o;
    }
    __shared__ float sp[256];
    sp[t] = csum;
    __syncthreads();
    if (t < 32) {
        float s = 0.f;
        for (int w = 0; w < 8; ++w) s += sp[w * 32 + t];
        atomicAdd(&msum[g * 32 + t], s);
    }
}

__global__ void ctx2_kernel(const float* __restrict__ msum, const float* __restrict__ W_att,
                            float* __restrict__ ctx, int N) {
    int t = threadIdx.x;
    if (t >= 64) return;
    int g = t >> 5, j = t & 31;
    float invN = 1.f / (float)N;
    float acc = 0.f;
    for (int i = 0; i < 32; ++i) acc += (msum[g * 32 + i] * invN) * W_att[i * 32 + j];
    ctx[g * 32 + j] = tanhf(acc);
}

__global__ void pool2_kernel(const float* __restrict__ a3, const float* __restrict__ ctx,
                             float* __restrict__ pooled, int N, int halfgrid) {
    int g = (blockIdx.x >= halfgrid) ? 1 : 0;
    int bid = blockIdx.x - g * halfgrid;
    int t = threadIdx.x;
    int j = t & 31;
    int hw = (bid * blockDim.x + t) >> 5;
    int nhw = (halfgrid * blockDim.x) >> 5;
    const float* base = a3 + (size_t)g * N * 32;
    float cj = ctx[g * 32 + j];
    float local = 0.f;
    for (int n = hw; n < N; n += nhw) {
        float v = base[(size_t)n * 32 + j];
        float d = v * cj;
        #pragma unroll
        for (int off = 16; off; off >>= 1) d += __shfl_xor(d, off);
        float s = 1.f / (1.f + __expf(-d));
        local += s * v;
    }
    __shared__ float sp[256];
    sp[t] = local;
    __syncthreads();
    if (t < 32) {
        float s = 0.f;
        for (int w = 0; w < 8; ++w) s += sp[w * 32 + t];
        atomicAdd(&pooled[g * 32 + t], s);
    }
}

__global__ void ntn_kernel(const float* __restrict__ p1, const float* __restrict__ p2,
                           const float* __restrict__ W_tn, const float* __restrict__ W_block,
                           const float* __restrict__ b_tn, float* __restrict__ out) {
    int k = threadIdx.x;
    if (k >= 16) return;
    float sc = 0.f;
    for (int i = 0; i < 32; ++i) {
        float e1 = p1[i];
        for (int j = 0; j < 32; ++j) sc += e1 * W_tn[i * 512 + j * 16 + k] * p2[j];
    }
    float bl = 0.f;
    for (int j = 0; j < 32; ++j)
        bl += W_block[k * 64 + j] * p1[j] + W_block[k * 64 + 32 + j] * p2[j];
    float v = sc + bl + b_tn[k];
    out[k] = v > 0.f ? v : 0.f;
}

extern "C" void kernel_launch(void* const* d_in, const int* in_sizes, int n_in,
                              void* d_out, int out_size, void* d_ws, size_t ws_size,
                              hipStream_t stream) {
    const float* f1     = (const float*)d_in[0];
    const int*   ei1    = (const int*)  d_in[1];
    const float* f2     = (const float*)d_in[2];
    const int*   ei2    = (const int*)  d_in[3];
    const float* W1     = (const float*)d_in[4];
    const float* b1     = (const float*)d_in[5];
    const float* W2     = (const float*)d_in[6];
    const float* b2     = (const float*)d_in[7];
    const float* W3     = (const float*)d_in[8];
    const float* b3     = (const float*)d_in[9];
    const float* W_att  = (const float*)d_in[10];
    const float* W_tn   = (const float*)d_in[11];
    const float* W_blk  = (const float*)d_in[12];
    const float* b_tn   = (const float*)d_in[13];

    int N = in_sizes[0] / 64;
    int E = in_sizes[1] / 2;
    int M = 2 * N;
    int E2 = 2 * E;

    char* ws = (char*)d_ws;
    size_t off = 0;
    auto alloc = [&](size_t bytes) -> void* {
        void* p = ws + off;
        off += (bytes + 511) & ~(size_t)511;
        return p;
    };
    _Float16*  xsA     = (_Float16*) alloc((size_t)M * 64 * sizeof(_Float16)); // xs0; h3s reuse
    _Float16*  xsB     = (_Float16*) alloc((size_t)M * 64 * sizeof(_Float16)); // xs1
    _Float16*  tH      = (_Float16*) alloc((size_t)M * 64 * sizeof(_Float16)); // t1 / t2
    float*     a3      = (float*)    alloc((size_t)M * 32 * sizeof(float));    // a3 (f32)
    int*       col     = (int*)      alloc((size_t)E2 * sizeof(int));
    int*       row_ptr = (int*)      alloc((size_t)(M + 1) * sizeof(int));
    int*       counts  = (int*)      alloc((size_t)M * sizeof(int));
    float*     dinv    = (float*)    alloc((size_t)M * sizeof(float));
    int*       bsum    = (int*)      alloc(256 * sizeof(int));
    _Float16*  pk      = (_Float16*) alloc(10240 * sizeof(_Float16));
    float*     smalls  = (float*)    alloc(256 * sizeof(float));
    float* msum   = smalls;        // [64]
    float* pooled = smalls + 64;   // [64]
    float* ctx    = smalls + 128;  // [64]
    _Float16* pk1 = pk, *pk2 = pk + 4096, *pk3 = pk + 8192;

    hipMemsetAsync(smalls, 0, 256 * sizeof(float), stream);
    hipMemsetAsync(counts, 0, (size_t)M * sizeof(int), stream);

    int eb = (E2 + 255) / 256;
    int P  = (M + 1023) / 1024;

    // CSR build
    count2_kernel<<<eb, 256, 0, stream>>>(ei1, ei2, E, N, counts);
    scanA_kernel<<<P, 256, 0, stream>>>(counts, bsum, M);
    scanB_kernel<<<1, 256, 0, stream>>>(bsum, P, row_ptr, M);
    scanC_kernel<<<P, 256, 0, stream>>>(counts, bsum, row_ptr, dinv, M);
    const int BPS = 128;   // blocks per dst-slice
    fill2_kernel<<<8 * BPS, 256, 0, stream>>>(ei1, ei2, E, N, row_ptr, counts, col, BPS);

    // Weight packing + pre-scaled f16 input table
    packW_kernel<<<40, 256, 0, stream>>>(W1, W2, W3, pk);
    int cvb = (M * 64 / 4 + 255) / 256;
    scale0_kernel<<<cvb, 256, 0, stream>>>(f1, f2, dinv, xsA, N * 64);

    // GCN stack
    int nb64 = (M * 64 + 255) / 256;             // wave-per-node agg
    int gw   = ((M / 16) + 3) / 4;               // MFMA: 4 waves/block, 16 rows/wave
    agg64_kernel<<<nb64, 256, 0, stream>>>(xsA, tH, row_ptr, col, dinv, M);               // t1
    mfma_gemm64_kernel<<<gw, 256, 0, stream>>>(tH, xsB, pk1, b1, dinv, M);                // xs1
    agg64_kernel<<<nb64, 256, 0, stream>>>(xsB, tH, row_ptr, col, dinv, M);               // t2
    mfma_gemm64_32_kernel<<<gw, 256, 0, stream>>>(tH, xsA, pk2, pk3, b2, dinv, M);        // h3s

    const int HG = 512;
    agg32_colsum_kernel<<<2 * HG, 256, 0, stream>>>(xsA, a3, row_ptr, col, dinv, b3, msum, N, HG);

    ctx2_kernel<<<1, 64, 0, stream>>>(msum, W_att, ctx, N);
    pool2_kernel<<<2 * 256, 256, 0, stream>>>(a3, ctx, pooled, N, 256);
    ntn_kernel<<<1, 64, 0, stream>>>(pooled, pooled + 32, W_tn, W_blk, b_tn, (float*)d_out);
}